// Round 16
// baseline (270.435 us; speedup 1.0000x reference)
//
#include <hip/hip_runtime.h>
#include <hip/hip_bf16.h>

// ---- problem constants ----
#define OUT_CH   31
#define COEF_LEN 7688                 // 31*31*8
#define NPIX     16384                // 128*128
#define CHUNKS   31                   // KAN input channels (independent param groups)
#define NFRG     24                   // param fragments per chunk (384 padded M rows)
#define NR       9                    // K-steps: r = ky*3+kx; k-in-step = conv channel ci
#define FRAG_U16 512                  // u16 per fragment (64 lanes x 8)
#define STEP_U16 (NFRG*FRAG_U16)      // 12288 u16 per (chunk,r) step
#define BP3_B    ((size_t)CHUNKS*NR*STEP_U16*2)        // 6,856,704
#define P1_B     ((size_t)OUT_CH*NPIX*4)               // 2,031,616
#define WS_NEED  (BP3_B + P1_B)                        // 8,888,320

using f32x4 = __attribute__((ext_vector_type(4))) float;
using s16x8 = __attribute__((ext_vector_type(8))) short;

__device__ __forceinline__ unsigned short f2bf(float f) {
    unsigned int u = __float_as_uint(f);
    unsigned int r = (u + 0x7FFFu + ((u >> 16) & 1u)) >> 16;
    return (unsigned short)r;
}

// ---------------------------------------------------------------------------
// Pack gen_w/gen_b into bf16 A-fragment layout (identical to R14, proven).
// Bias folded into GEMM: slab slot 31 = 1.0; A[ci=31] at r==4 carries gb[p].
//  bp3[i][r][f][lane][8] bf16.  M-row m = lane&15; k-in-step ci = (lane>>4)*8+jj.
//  param identity: o = (m>>2)*8 + f/3, jslot = (f%3)*4 + (m&3)
//    jslot 0..7 = coef j, 8 = univ, 9 = res, 10..11 = zero pad
// ---------------------------------------------------------------------------
__global__ void pack_kernel(const float* __restrict__ gw, const float* __restrict__ gb,
                            unsigned short* __restrict__ bp) {
    const int NMAIN = CHUNKS * NFRG * 64;          // 47616
    int tt = blockIdx.x * 256 + threadIdx.x;
    if (tt >= NMAIN) return;
    int lane = tt & 63;
    int u = tt >> 6;
    int f = u % NFRG;
    int i = u / NFRG;
    int m = lane & 15, q8 = lane >> 4;
    int o = (m >> 2) * 8 + f / 3;
    int jslot = (f % 3) * 4 + (m & 3);
    int p = -1;
    if (o < OUT_CH && jslot < 10) {
        if (jslot < 8)       p = i * 248 + o * 8 + jslot;
        else if (jslot == 8) p = COEF_LEN + i * 31 + o;
        else                 p = COEF_LEN + 961 + i * 31 + o;
    }
    s16x8 vr[NR];
    #pragma unroll
    for (int r = 0; r < NR; ++r)
        #pragma unroll
        for (int jj = 0; jj < 8; ++jj) vr[r][jj] = 0;
    #pragma unroll
    for (int jj = 0; jj < 8; ++jj) {
        int ci = q8 * 8 + jj;
        if (p >= 0) {
            if (ci < 31) {
                const float* gr = gw + (long)p * 279 + ci * 9;
                #pragma unroll
                for (int r = 0; r < NR; ++r) vr[r][jj] = (short)f2bf(gr[r]);
            } else {
                vr[4][jj] = (short)f2bf(gb[p]);   // bias channel, center tap only
            }
        }
    }
    #pragma unroll
    for (int r = 0; r < NR; ++r)
        *reinterpret_cast<s16x8*>(bp + (((size_t)i * NR + r) * NFRG + f) * FRAG_U16 + lane * 8) = vr[r];
}

// ---------------------------------------------------------------------------
// Fused conv-GEMM + KAN epilogue — occupancy-first rebuild of R14.
// 256-thr blocks (4 waves): block granularity 1 wave/SIMD, so 3 blocks/CU =
// 3 waves/SIMD once VGPR <= ~85 (empirical: waves/SIMD ~ 256/VGPR; R14's
// 120 regs pinned 2/SIMD -> MfmaUtil 46% ceiling). Register diet:
//  - table epilogue (Wt f32 w8-records, SLt bf16 silu) built once per block
//  - NO pa double-buffer (TLP hides L2 latency instead)
//  - pbv streamed in the pg loop; single-base + immediate LDS addressing
// Enforced by __launch_bounds__(256,3). LDS 52.2 KB/block -> 3 blocks fit.
// Grid 1024 = 128 rows x 2 ch x 2 cg x 2 fh; cg = bid&1 pins a 3.46 MB param
// slice per XCD L2. A streams global->VGPR (one consumer wave per frag).
// Output: cg0 -> out, cg1 -> ws partial (+reduce); chained fallback if ws small.
// ---------------------------------------------------------------------------
__global__ void __launch_bounds__(256, 3)
main_kernel(const float* __restrict__ x, const unsigned short* __restrict__ bp3,
            float* __restrict__ dst0, float* __restrict__ dst1,
            int two_cg, int c0_in, int nc_in, int add_in) {
    __shared__ unsigned short slab[3 * 66 * 40];   // 15840 B
    __shared__ float Wt[64 * 132];                 // 33792 B (w8-records, 16B-aligned rows)
    __shared__ unsigned short SLt[64 * 20];        // 2560 B (bf16 silu)
    const int tid = threadIdx.x;
    const int bid = blockIdx.x;
    int row, ch, c0, nc, addf, fh;
    float* dst;
    if (two_cg) {
        int cg = bid & 1;          // XCD = bid%8 -> cg fixed per XCD (L2 pin)
        fh = (bid >> 1) & 1;
        ch = (bid >> 2) & 1;
        row = bid >> 3;
        c0 = cg ? 16 : 0;
        nc = cg ? 15 : 16;
        dst = cg ? dst1 : dst0;
        addf = 0;
    } else {
        fh = bid & 1; ch = (bid >> 1) & 1; row = bid >> 2;
        c0 = c0_in; nc = nc_in; dst = dst0; addf = add_in;
    }

    // slab: rows row-1..row+1, cols ch*64-1 .. ch*64+64; slot31 = 1.0 (bias col)
    for (int idx = tid; idx < 3 * 66 * 40; idx += 256) {
        int slot = idx % 40;
        int t = idx / 40;
        int cc = t % 66;
        int rr = t / 66;
        int hh = row - 1 + rr, ww = ch * 64 - 1 + cc;
        unsigned short v = 0;
        if (slot < 31) {
            if ((unsigned)hh < 128u && (unsigned)ww < 128u)
                v = f2bf(x[slot * NPIX + hh * 128 + ww]);
        } else if (slot == 31) {
            v = 0x3F80;   // 1.0 bf16
        }
        slab[(rr * 66 + cc) * 40 + slot] = v;
    }

    // spline/silu tables: once per (pixel, chunk), from f32 x (center pixels)
    for (int idx = tid; idx < nc * 64; idx += 256) {
        int px = idx & 63;
        int k = idx >> 6;
        float xv = x[(size_t)(c0 + k) * NPIX + row * 128 + ch * 64 + px];
        float u5 = (xv + 1.0f) * 2.5f;
        float cf = fminf(fmaxf(floorf(u5), 0.f), 4.f);
        int ccb = (int)cf;
        float t = u5 - cf;
        float omt = 1.f - t;
        float t2v = t * t, t3v = t2v * t;
        float bw0 = omt * omt * omt * (1.f / 6.f);
        float bw3 = t3v * (1.f / 6.f);
        float bw1 = 0.5f * t3v - t2v + (2.f / 3.f);
        float bw2 = 1.f - bw0 - bw1 - bw3;         // partition of unity
        float* wr = Wt + px * 132 + k * 8;
        *reinterpret_cast<f32x4*>(wr) = (f32x4){0.f, 0.f, 0.f, 0.f};
        *reinterpret_cast<f32x4*>(wr + 4) = (f32x4){0.f, 0.f, 0.f, 0.f};
        wr[ccb] = bw0; wr[ccb + 1] = bw1; wr[ccb + 2] = bw2; wr[ccb + 3] = bw3;
        SLt[px * 20 + k] = f2bf(xv / (1.f + __expf(-xv)));
    }
    __syncthreads();
    // ---- no further barriers; slab/Wt/SLt are read-only below ----

    const int lane = tid & 63;
    const int fi = fh * 4 + (tid >> 6);   // 0..7: this wave's frag triple
    const int q = lane >> 4;
    const int pix16 = lane & 15;

    // single-base + compile-time-immediate LDS addressing
    const char* sbase = ((const char*)slab) + pix16 * 80 + q * 16;
    const float* wbase = Wt + pix16 * 132;
    const unsigned short* slbase = SLt + pix16 * 20;

    float oreg[4] = {0.f, 0.f, 0.f, 0.f};

    #pragma unroll 1
    for (int k = 0; k < nc; ++k) {
        const unsigned short* aw = bp3
            + ((size_t)(c0 + k) * NR * NFRG + fi * 3) * FRAG_U16 + lane * 8;

        f32x4 acc[3][4];
        #pragma unroll
        for (int fl = 0; fl < 3; ++fl)
            #pragma unroll
            for (int pg = 0; pg < 4; ++pg)
                acc[fl][pg] = (f32x4){0.f, 0.f, 0.f, 0.f};   // bias comes via GEMM

        #pragma unroll
        for (int r = 0; r < NR; ++r) {
            // single-buffered A: 3 frag loads (L2 latency covered by 3-wave TLP)
            s16x8 pa0 = *reinterpret_cast<const s16x8*>(aw + r * STEP_U16);
            s16x8 pa1 = *reinterpret_cast<const s16x8*>(aw + r * STEP_U16 + FRAG_U16);
            s16x8 pa2 = *reinterpret_cast<const s16x8*>(aw + r * STEP_U16 + 2 * FRAG_U16);
            const int roff = ((r / 3) * 66 + (r % 3)) * 80;
            __builtin_amdgcn_s_setprio(1);
            #pragma unroll
            for (int pg = 0; pg < 4; ++pg) {
                s16x8 pb = *reinterpret_cast<const s16x8*>(sbase + pg * 1280 + roff);
                acc[0][pg] = __builtin_amdgcn_mfma_f32_16x16x32_bf16(pa0, pb, acc[0][pg], 0, 0, 0);
                acc[1][pg] = __builtin_amdgcn_mfma_f32_16x16x32_bf16(pa1, pb, acc[1][pg], 0, 0, 0);
                acc[2][pg] = __builtin_amdgcn_mfma_f32_16x16x32_bf16(pa2, pb, acc[2][pg], 0, 0, 0);
            }
            __builtin_amdgcn_s_setprio(0);
        }

        // table epilogue: 2 b128 + 1 b16 LDS reads + 10 fma per pg
        #pragma unroll
        for (int pg = 0; pg < 4; ++pg) {
            const float* wr = wbase + pg * (16 * 132) + k * 8;
            f32x4 wlo = *reinterpret_cast<const f32x4*>(wr);
            f32x4 whi = *reinterpret_cast<const f32x4*>(wr + 4);
            unsigned short slb = slbase[pg * (16 * 20) + k];
            float sl = __uint_as_float((unsigned)slb << 16);
            float sp = wlo[0] * acc[0][pg][0];
            sp = fmaf(wlo[1], acc[0][pg][1], sp);
            sp = fmaf(wlo[2], acc[0][pg][2], sp);
            sp = fmaf(wlo[3], acc[0][pg][3], sp);
            sp = fmaf(whi[0], acc[1][pg][0], sp);
            sp = fmaf(whi[1], acc[1][pg][1], sp);
            sp = fmaf(whi[2], acc[1][pg][2], sp);
            sp = fmaf(whi[3], acc[1][pg][3], sp);
            oreg[pg] = fmaf(acc[2][pg][0], sp, fmaf(sl, acc[2][pg][1], oreg[pg]));
        }
    }

    // write: lane's single output channel o = q*8 + fi (o==31 is pad -> skip)
    const int o = q * 8 + fi;
    if (o < OUT_CH) {
        #pragma unroll
        for (int pg = 0; pg < 4; ++pg) {
            size_t gi = (size_t)o * NPIX + row * 128 + ch * 64 + pg * 16 + pix16;
            if (addf) dst[gi] += oreg[pg];
            else      dst[gi]  = oreg[pg];
        }
    }
}

__global__ void reduce_kernel(const float* __restrict__ p1, float* __restrict__ out) {
    int e = blockIdx.x * 256 + threadIdx.x;
    if (e < OUT_CH * NPIX) out[e] += p1[e];
}

extern "C" void kernel_launch(void* const* d_in, const int* in_sizes, int n_in,
                              void* d_out, int out_size, void* d_ws, size_t ws_size,
                              hipStream_t stream) {
    const float* x  = (const float*)d_in[0];   // (1,31,128,128)
    const float* gw = (const float*)d_in[1];   // (9610,31,3,3)
    const float* gb = (const float*)d_in[2];   // (9610,)
    float* outp = (float*)d_out;               // (1,31,128,128)
    unsigned short* bpack = (unsigned short*)d_ws;          // 6,856,704 B
    float* p1 = (float*)((char*)d_ws + BP3_B);

    const int NMAIN = CHUNKS * NFRG * 64;                   // 47616
    pack_kernel<<<(NMAIN + 255) / 256, 256, 0, stream>>>(gw, gb, bpack);

    if (ws_size >= WS_NEED) {
        // 1024 blocks = 128 rows x 2 ch x 2 cg x 2 fh; cg0 -> out, cg1 -> p1
        main_kernel<<<1024, 256, 0, stream>>>(x, bpack, outp, p1, 1, 0, 0, 0);
        reduce_kernel<<<(OUT_CH * NPIX + 255) / 256, 256, 0, stream>>>(p1, outp);
    } else {
        // chained fallback: two sequential dispatches (512 blocks each) through d_out
        main_kernel<<<512, 256, 0, stream>>>(x, bpack, outp, nullptr, 0, 0, 16, 0);
        main_kernel<<<512, 256, 0, stream>>>(x, bpack, outp, nullptr, 0, 16, 15, 1);
    }
}

// Round 17
// 109.380 us; speedup vs baseline: 2.4724x; 2.4724x over previous
//
#include <hip/hip_runtime.h>
#include <hip/hip_bf16.h>

// ---- problem constants ----
#define OUT_CH   31
#define COEF_LEN 7688                 // 31*31*8
#define NPIX     16384                // 128*128
#define CHUNKS   31                   // KAN input channels (independent param groups)
#define NFRG     24                   // param fragments per chunk (384 padded M rows)
#define NR       9                    // K-steps: r = ky*3+kx; k-in-step = conv channel ci
#define FRAG_U16 512                  // u16 per fragment (64 lanes x 8)
#define STEP_U16 (NFRG*FRAG_U16)      // 12288 u16 per (chunk,r) step
#define BP3_B    ((size_t)CHUNKS*NR*STEP_U16*2)        // 6,856,704
#define P1_B     ((size_t)OUT_CH*NPIX*4)               // 2,031,616
#define WS_NEED  (BP3_B + P1_B)                        // 8,888,320

using f32x4 = __attribute__((ext_vector_type(4))) float;
using s16x8 = __attribute__((ext_vector_type(8))) short;

__device__ __forceinline__ unsigned short f2bf(float f) {
    unsigned int u = __float_as_uint(f);
    unsigned int r = (u + 0x7FFFu + ((u >> 16) & 1u)) >> 16;
    return (unsigned short)r;
}

// ---------------------------------------------------------------------------
// Pack gen_w/gen_b into bf16 A-fragment layout (R14-proven, unchanged).
// Bias folded into GEMM: slab slot 31 = 1.0; A[ci=31] at r==4 carries gb[p].
//  bp3[i][r][f][lane][8] bf16.  M-row m = lane&15; k-in-step ci = (lane>>4)*8+jj.
//  param identity: o = (m>>2)*8 + f/3, jslot = (f%3)*4 + (m&3)
//    jslot 0..7 = coef j, 8 = univ, 9 = res, 10..11 = zero pad
// ---------------------------------------------------------------------------
__global__ void pack_kernel(const float* __restrict__ gw, const float* __restrict__ gb,
                            unsigned short* __restrict__ bp) {
    const int NMAIN = CHUNKS * NFRG * 64;          // 47616
    int tt = blockIdx.x * 256 + threadIdx.x;
    if (tt >= NMAIN) return;
    int lane = tt & 63;
    int u = tt >> 6;
    int f = u % NFRG;
    int i = u / NFRG;
    int m = lane & 15, q8 = lane >> 4;
    int o = (m >> 2) * 8 + f / 3;
    int jslot = (f % 3) * 4 + (m & 3);
    int p = -1;
    if (o < OUT_CH && jslot < 10) {
        if (jslot < 8)       p = i * 248 + o * 8 + jslot;
        else if (jslot == 8) p = COEF_LEN + i * 31 + o;
        else                 p = COEF_LEN + 961 + i * 31 + o;
    }
    s16x8 vr[NR];
    #pragma unroll
    for (int r = 0; r < NR; ++r)
        #pragma unroll
        for (int jj = 0; jj < 8; ++jj) vr[r][jj] = 0;
    #pragma unroll
    for (int jj = 0; jj < 8; ++jj) {
        int ci = q8 * 8 + jj;
        if (p >= 0) {
            if (ci < 31) {
                const float* gr = gw + (long)p * 279 + ci * 9;
                #pragma unroll
                for (int r = 0; r < NR; ++r) vr[r][jj] = (short)f2bf(gr[r]);
            } else {
                vr[4][jj] = (short)f2bf(gb[p]);   // bias channel, center tap only
            }
        }
    }
    #pragma unroll
    for (int r = 0; r < NR; ++r)
        *reinterpret_cast<s16x8*>(bp + (((size_t)i * NR + r) * NFRG + f) * FRAG_U16 + lane * 8) = vr[r];
}

// ---------------------------------------------------------------------------
// Fused conv-GEMM + KAN epilogue. R14 structure verbatim (best verified:
// 109 us main, VGPR 120, no spill) with ONE change: table-driven epilogue.
//  - A streams GLOBAL->VGPR, pa[2][3] reg-dbuf, per-chunk loop (NOT flattened
//    — R15's flattening blew the 128-reg cap), one __syncthreads.
//  - Wt[px][k][8] f32 scattered-spline-weight records (132-f32 px stride ->
//    2-way bank conflict = free) + SLt bf16 silu, built once per block:
//    epilogue/pg = 2 ds_read_b128 + 1 b16 + 10 fma (removes ~110 VALU +
//    24 shfl per chunk per wave; R14 VALUBusy 31% -> ~20%).
// Grid 512 = 128 rows x 2 ch x 2 cg; cg = bid&1 pins a 3.46 MB param slice
// per XCD L2. Output: cg0 -> out, cg1 -> ws partial (+reduce); chained
// fallback if ws small.
// ---------------------------------------------------------------------------
__global__ void __launch_bounds__(512, 1)
main_kernel(const float* __restrict__ x, const unsigned short* __restrict__ bp3,
            float* __restrict__ dst0, float* __restrict__ dst1,
            int two_cg, int c0_in, int nc_in, int add_in) {
    __shared__ unsigned short slab[3 * 66 * 40];   // 15840 B
    __shared__ float Wt[64 * 132];                 // 33792 B
    __shared__ unsigned short SLt[64 * 20];        // 2560 B
    const int tid = threadIdx.x;
    const int bid = blockIdx.x;
    int row, ch, c0, nc, addf;
    float* dst;
    if (two_cg) {
        int cg = bid & 1;          // XCD = bid%8 -> cg fixed per XCD (L2 pin)
        ch = (bid >> 1) & 1;
        row = bid >> 2;
        c0 = cg ? 16 : 0;
        nc = cg ? 15 : 16;
        dst = cg ? dst1 : dst0;
        addf = 0;
    } else {
        ch = bid & 1; row = bid >> 1;
        c0 = c0_in; nc = nc_in; dst = dst0; addf = add_in;
    }

    // slab: rows row-1..row+1, cols ch*64-1 .. ch*64+64; slot31 = 1.0 (bias col)
    for (int idx = tid; idx < 3 * 66 * 40; idx += 512) {
        int slot = idx % 40;
        int t = idx / 40;
        int cc = t % 66;
        int rr = t / 66;
        int hh = row - 1 + rr, ww = ch * 64 - 1 + cc;
        unsigned short v = 0;
        if (slot < 31) {
            if ((unsigned)hh < 128u && (unsigned)ww < 128u)
                v = f2bf(x[slot * NPIX + hh * 128 + ww]);
        } else if (slot == 31) {
            v = 0x3F80;   // 1.0 bf16
        }
        slab[(rr * 66 + cc) * 40 + slot] = v;
    }

    // spline/silu tables: once per (pixel, chunk), from f32 x (center pixels)
    for (int idx = tid; idx < nc * 64; idx += 512) {
        int px = idx & 63;
        int k = idx >> 6;
        float xv = x[(size_t)(c0 + k) * NPIX + row * 128 + ch * 64 + px];
        float u5 = (xv + 1.0f) * 2.5f;
        float cf = fminf(fmaxf(floorf(u5), 0.f), 4.f);
        int ccb = (int)cf;
        float t = u5 - cf;
        float omt = 1.f - t;
        float t2v = t * t, t3v = t2v * t;
        float bw0 = omt * omt * omt * (1.f / 6.f);
        float bw3 = t3v * (1.f / 6.f);
        float bw1 = 0.5f * t3v - t2v + (2.f / 3.f);
        float bw2 = 1.f - bw0 - bw1 - bw3;         // partition of unity
        float* wr = Wt + px * 132 + k * 8;
        *reinterpret_cast<f32x4*>(wr) = (f32x4){0.f, 0.f, 0.f, 0.f};
        *reinterpret_cast<f32x4*>(wr + 4) = (f32x4){0.f, 0.f, 0.f, 0.f};
        wr[ccb] = bw0; wr[ccb + 1] = bw1; wr[ccb + 2] = bw2; wr[ccb + 3] = bw3;
        SLt[px * 20 + k] = f2bf(xv / (1.f + __expf(-xv)));
    }
    __syncthreads();
    // ---- no further barriers; slab/Wt/SLt are read-only below ----

    const int lane = tid & 63;
    const int fi = tid >> 6;              // 0..7: this wave's frag triple
    const int q = lane >> 4;
    const int pix16 = lane & 15;
    const char* slabb = (const char*)slab;

    int sa[4];
    #pragma unroll
    for (int pg = 0; pg < 4; ++pg)
        sa[pg] = (pg * 16 + pix16) * 80 + q * 16;   // slab byte offsets

    float oreg[4] = {0.f, 0.f, 0.f, 0.f};

    #pragma unroll 1
    for (int k = 0; k < nc; ++k) {
        const unsigned short* aw = bp3
            + ((size_t)(c0 + k) * NR * NFRG + fi * 3) * FRAG_U16 + lane * 8;

        s16x8 pa[2][3];
        #pragma unroll
        for (int fl = 0; fl < 3; ++fl)
            pa[0][fl] = *reinterpret_cast<const s16x8*>(aw + fl * FRAG_U16);

        f32x4 acc[3][4];
        #pragma unroll
        for (int fl = 0; fl < 3; ++fl)
            #pragma unroll
            for (int pg = 0; pg < 4; ++pg)
                acc[fl][pg] = (f32x4){0.f, 0.f, 0.f, 0.f};   // bias comes via GEMM

        #pragma unroll
        for (int r = 0; r < NR; ++r) {
            if (r + 1 < NR) {    // reg-dbuf prefetch; static index (r unrolled)
                #pragma unroll
                for (int fl = 0; fl < 3; ++fl)
                    pa[(r + 1) & 1][fl] = *reinterpret_cast<const s16x8*>(
                        aw + (r + 1) * STEP_U16 + fl * FRAG_U16);
            }
            const int roff = ((r / 3) * 66 + (r % 3)) * 80;
            s16x8 pbv[4];
            #pragma unroll
            for (int pg = 0; pg < 4; ++pg)
                pbv[pg] = *reinterpret_cast<const s16x8*>(slabb + sa[pg] + roff);

            __builtin_amdgcn_s_setprio(1);
            #pragma unroll
            for (int fl = 0; fl < 3; ++fl)
                #pragma unroll
                for (int pg = 0; pg < 4; ++pg)
                    acc[fl][pg] = __builtin_amdgcn_mfma_f32_16x16x32_bf16(
                        pa[r & 1][fl], pbv[pg], acc[fl][pg], 0, 0, 0);
            __builtin_amdgcn_s_setprio(0);
        }

        // table epilogue: 2 b128 + 1 b16 LDS reads + 10 fma per pg
        #pragma unroll
        for (int pg = 0; pg < 4; ++pg) {
            const float* wr = Wt + (pg * 16 + pix16) * 132 + k * 8;
            f32x4 wlo = *reinterpret_cast<const f32x4*>(wr);
            f32x4 whi = *reinterpret_cast<const f32x4*>(wr + 4);
            unsigned short slb = SLt[(pg * 16 + pix16) * 20 + k];
            float sl = __uint_as_float((unsigned)slb << 16);
            float sp = wlo[0] * acc[0][pg][0];
            sp = fmaf(wlo[1], acc[0][pg][1], sp);
            sp = fmaf(wlo[2], acc[0][pg][2], sp);
            sp = fmaf(wlo[3], acc[0][pg][3], sp);
            sp = fmaf(whi[0], acc[1][pg][0], sp);
            sp = fmaf(whi[1], acc[1][pg][1], sp);
            sp = fmaf(whi[2], acc[1][pg][2], sp);
            sp = fmaf(whi[3], acc[1][pg][3], sp);
            oreg[pg] = fmaf(acc[2][pg][0], sp, fmaf(sl, acc[2][pg][1], oreg[pg]));
        }
    }

    // write: lane's single output channel o = q*8 + fi (o==31 is pad -> skip)
    const int o = q * 8 + fi;
    if (o < OUT_CH) {
        #pragma unroll
        for (int pg = 0; pg < 4; ++pg) {
            size_t gi = (size_t)o * NPIX + row * 128 + ch * 64 + pg * 16 + pix16;
            if (addf) dst[gi] += oreg[pg];
            else      dst[gi]  = oreg[pg];
        }
    }
}

__global__ void reduce_kernel(const float* __restrict__ p1, float* __restrict__ out) {
    int e = blockIdx.x * 256 + threadIdx.x;
    if (e < OUT_CH * NPIX) out[e] += p1[e];
}

extern "C" void kernel_launch(void* const* d_in, const int* in_sizes, int n_in,
                              void* d_out, int out_size, void* d_ws, size_t ws_size,
                              hipStream_t stream) {
    const float* x  = (const float*)d_in[0];   // (1,31,128,128)
    const float* gw = (const float*)d_in[1];   // (9610,31,3,3)
    const float* gb = (const float*)d_in[2];   // (9610,)
    float* outp = (float*)d_out;               // (1,31,128,128)
    unsigned short* bpack = (unsigned short*)d_ws;          // 6,856,704 B
    float* p1 = (float*)((char*)d_ws + BP3_B);

    const int NMAIN = CHUNKS * NFRG * 64;                   // 47616
    pack_kernel<<<(NMAIN + 255) / 256, 256, 0, stream>>>(gw, gb, bpack);

    if (ws_size >= WS_NEED) {
        // 512 blocks = 128 rows x 2 col-halves x 2 cg; cg0 -> out, cg1 -> p1
        main_kernel<<<512, 512, 0, stream>>>(x, bpack, outp, p1, 1, 0, 0, 0);
        reduce_kernel<<<(OUT_CH * NPIX + 255) / 256, 256, 0, stream>>>(p1, outp);
    } else {
        // chained fallback: two sequential dispatches (256 blocks each) through d_out
        main_kernel<<<256, 512, 0, stream>>>(x, bpack, outp, nullptr, 0, 0, 16, 0);
        main_kernel<<<256, 512, 0, stream>>>(x, bpack, outp, nullptr, 0, 16, 15, 1);
    }
}